// Round 9
// baseline (2071.894 us; speedup 1.0000x reference)
//
#include <hip/hip_runtime.h>

#define NNODES 50000
#define HDIM 256
#define NLAYERS 4
#define NEDGES 800000
#define FIN 1280
#define LDOUT 1024

typedef _Float16 f16;
typedef __attribute__((ext_vector_type(8))) _Float16 f16x8;
typedef __attribute__((ext_vector_type(4))) _Float16 f16x4;
typedef __attribute__((ext_vector_type(4))) float f32x4;

enum { DSRC_H = 0, DSRC_MULH = 1, DSRC_ADDRELU = 2, DSRC_CATH = 3 };
enum { DEPI_W2W1H = 0, DEPI_MASKXG = 1, DEPI_CATH = 2 };

// ---------------------------------------------------------------------------
// Direct-fragment MFMA GEMM: NO LDS, NO barriers.  One wave = 16 rows x 128
// cols.  A-fragment loaded straight from global (lane l: row row0+(l&15),
// 8 contiguous f16 at k=(l>>4)*8) — valid because A is f16 row-major and the
// MFMA A layout (refcheck-validated R3-R7) is row=l&15, k=(l>>4)*8+j.
// B col-major Wt: lane l col=col0+cf*16+(l&15), k=(l>>4)*8+j.
// C/D: col=l&15, row=(l>>4)*4+j.
// RACE RULE (R8 lesson): outputs must never alias any GEMM input of the
// same dispatch — x is double-buffered (xcur -> xnew).
// blockIdx.y: bit0 = column half, bit1 = weight select (W2W1 fusion).
// ---------------------------------------------------------------------------
template<int SRC, int EPI, int KTILES>
__global__ __launch_bounds__(256) void dgemm_k(
    const float* __restrict__ A1,     // aggf (ADDRELU)
    const f16*  __restrict__ A3,      // xcur / agg2
    const f16*  __restrict__ A5,      // maskh (MULH) / xw1h (ADDRELU)
    const f16*  __restrict__ A4,      // xcur (CATH, k>=256)
    const f16*  __restrict__ Xh,      // xcur (MASKXG epilogue)
    const f16*  __restrict__ Wt,      // [256 cols][K] col-major f16
    const f16*  __restrict__ Wt2,     // W1 (W2W1 pair)
    const float* __restrict__ bias,
    const float* __restrict__ bias2,
    float* __restrict__ Cf, int ldc,
    f16*  __restrict__ Ch,
    f16*  __restrict__ Ch2)
{
    constexpr int K = KTILES * 32;
    const int tid = threadIdx.x;
    const int l = tid & 63;
    const int wv = tid >> 6;
    const int row0 = blockIdx.x * 64 + wv * 16;
    if (row0 >= NNODES) return;                  // no barriers -> safe exit
    const int by = blockIdx.y;
    const int col0 = (by & 1) * 128;
    const int wsel = by >> 1;

    const int arow = row0 + (l & 15);
    const int ak = (l >> 4) * 8;

    const f16* Wb = (EPI == DEPI_W2W1H && wsel) ? Wt2 : Wt;
    const f16* bp[8];
    #pragma unroll
    for (int cf = 0; cf < 8; ++cf)
        bp[cf] = Wb + (size_t)(col0 + cf * 16 + (l & 15)) * K + ak;

    f32x4 acc[8] = {};

    auto LOADA = [&](int kt) -> f16x8 {
        const int k0 = kt * 32 + ak;
        if constexpr (SRC == DSRC_H) {
            return *(const f16x8*)(A3 + (size_t)arow * HDIM + k0);
        } else if constexpr (SRC == DSRC_MULH) {
            f16x8 h = *(const f16x8*)(A3 + (size_t)arow * HDIM + k0);
            f16x8 m = *(const f16x8*)(A5 + (size_t)arow * HDIM + k0);
            f16x8 r;
            #pragma unroll
            for (int i = 0; i < 8; ++i)
                r[i] = (f16)((float)h[i] * (float)m[i]);
            return r;
        } else if constexpr (SRC == DSRC_ADDRELU) {
            const float* p = A1 + (size_t)arow * HDIM + k0;
            float4 a0 = *(const float4*)(p);
            float4 a1 = *(const float4*)(p + 4);
            f16x8 w = *(const f16x8*)(A5 + (size_t)arow * HDIM + k0);
            f16x8 r;
            r[0] = (f16)fmaxf(a0.x + (float)w[0], 0.f);
            r[1] = (f16)fmaxf(a0.y + (float)w[1], 0.f);
            r[2] = (f16)fmaxf(a0.z + (float)w[2], 0.f);
            r[3] = (f16)fmaxf(a0.w + (float)w[3], 0.f);
            r[4] = (f16)fmaxf(a1.x + (float)w[4], 0.f);
            r[5] = (f16)fmaxf(a1.y + (float)w[5], 0.f);
            r[6] = (f16)fmaxf(a1.z + (float)w[6], 0.f);
            r[7] = (f16)fmaxf(a1.w + (float)w[7], 0.f);
            return r;
        } else { // DSRC_CATH
            if (kt < 8) return *(const f16x8*)(A3 + (size_t)arow * HDIM + kt * 32 + ak);
            else        return *(const f16x8*)(A4 + (size_t)arow * HDIM + (kt - 8) * 32 + ak);
        }
    };

    // depth-1 pipeline (full unroll -> copies become renames)
    f16x8 aC = LOADA(0);
    f16x8 bC[8];
    #pragma unroll
    for (int cf = 0; cf < 8; ++cf) bC[cf] = *(const f16x8*)(bp[cf]);

    #pragma unroll
    for (int kt = 0; kt < KTILES; ++kt) {
        f16x8 aN;
        f16x8 bN[8];
        if (kt + 1 < KTILES) {
            aN = LOADA(kt + 1);
            #pragma unroll
            for (int cf = 0; cf < 8; ++cf)
                bN[cf] = *(const f16x8*)(bp[cf] + (kt + 1) * 32);
        }
        #pragma unroll
        for (int cf = 0; cf < 8; ++cf)
            acc[cf] = __builtin_amdgcn_mfma_f32_16x16x32_f16(aC, bC[cf], acc[cf], 0, 0, 0);
        if (kt + 1 < KTILES) {
            aC = aN;
            #pragma unroll
            for (int cf = 0; cf < 8; ++cf) bC[cf] = bN[cf];
        }
    }

    // ---- epilogue
    #pragma unroll
    for (int j = 0; j < 4; ++j) {
        const int row = row0 + (l >> 4) * 4 + j;
        #pragma unroll
        for (int cf = 0; cf < 8; ++cf) {
            const int col = col0 + cf * 16 + (l & 15);
            float v = acc[cf][j];
            if constexpr (EPI == DEPI_W2W1H) {
                if (wsel == 0) Ch[(size_t)row * HDIM + col]  = (f16)(v + bias[col]);
                else           Ch2[(size_t)row * HDIM + col] = (f16)(v + bias2[col]);
            } else if constexpr (EPI == DEPI_MASKXG) {
                const float m = 1.f / (1.f + expf(-(v + bias[col])));
                Ch2[(size_t)row * HDIM + col] = (f16)m;
                Ch[(size_t)row * HDIM + col] =
                    (f16)((float)Xh[(size_t)row * HDIM + col] * m);
            } else { // DEPI_CATH
                const float r = fmaxf(v + bias[col], 0.f);
                Cf[(size_t)row * ldc + col] = r;
                Ch[(size_t)row * HDIM + col] = (f16)r;
            }
        }
    }
}

// ---------------------------------------------------------------------------
// lin0 GEMM (R7 structure, measured 149us): BM=64 x BN=256, BK=64, LDS
// double-buffer + depth-2 reg prefetch; blockIdx.y = K-half (K-split x2).
// ---------------------------------------------------------------------------
template<int KTILES>
__global__ __launch_bounds__(256) void lin0_k(
    const float* __restrict__ A1, int lda1,
    const f16*  __restrict__ WtA, const f16* __restrict__ WtB,
    float* __restrict__ Cf, float* __restrict__ Cf2)
{
    constexpr int K = KTILES * 64;
    __shared__ f16 Asm[2][4096];

    const int row0 = blockIdx.x * 64;
    const int by = blockIdx.y;
    const int tid = threadIdx.x;
    const int wv = tid >> 6;
    const int l = tid & 63;

    f32x4 acc[4][4] = {};

    const int sr = tid >> 2;
    const int sc0 = (tid & 3) * 16;
    const int grow = row0 + sr;
    const bool rok = grow < NNODES;
    const int kg = by * K;
    const int lane_base0 =
        (((sc0 >> 5) * 4 + (sr >> 4)) * 64 + (sr & 15) + (((sc0 & 31) >> 3) * 16)) * 8;
    const int lane_base1 = lane_base0 + 128;

    const f16* Wsel = by ? WtB : WtA;
    const f16* bp[4];
    #pragma unroll
    for (int cf = 0; cf < 4; ++cf)
        bp[cf] = Wsel + (size_t)(wv * 64 + cf * 16 + (l & 15)) * K + ((l >> 4) * 8);

    struct SReg { float4 f0, f1, f2, f3; };
    SReg RA, RB;

    auto LOAD = [&](SReg& r, int kt) {
        if (!rok) return;
        const float* p = A1 + (size_t)grow * lda1 + kg + kt * 64 + sc0;
        r.f0 = *(const float4*)(p + 0);  r.f1 = *(const float4*)(p + 4);
        r.f2 = *(const float4*)(p + 8);  r.f3 = *(const float4*)(p + 12);
    };

    auto COMMIT = [&](const SReg& r, int b) {
        f16x8 av0, av1;
        #pragma unroll
        for (int i = 0; i < 8; ++i) { av0[i] = (f16)0.f; av1[i] = (f16)0.f; }
        if (rok) {
            av0[0]=(f16)r.f0.x; av0[1]=(f16)r.f0.y; av0[2]=(f16)r.f0.z; av0[3]=(f16)r.f0.w;
            av0[4]=(f16)r.f1.x; av0[5]=(f16)r.f1.y; av0[6]=(f16)r.f1.z; av0[7]=(f16)r.f1.w;
            av1[0]=(f16)r.f2.x; av1[1]=(f16)r.f2.y; av1[2]=(f16)r.f2.z; av1[3]=(f16)r.f2.w;
            av1[4]=(f16)r.f3.x; av1[5]=(f16)r.f3.y; av1[6]=(f16)r.f3.z; av1[7]=(f16)r.f3.w;
        }
        *(f16x8*)(&Asm[b][lane_base0]) = av0;
        *(f16x8*)(&Asm[b][lane_base1]) = av1;
    };

    auto TILE = [&](int b, int kt) {
        f16x8 af[4][2];
        #pragma unroll
        for (int rf = 0; rf < 4; ++rf)
            #pragma unroll
            for (int kb = 0; kb < 2; ++kb)
                af[rf][kb] = *(const f16x8*)(&Asm[b][((kb * 4 + rf) * 64 + l) * 8]);
        f16x8 bfr[4][2];
        #pragma unroll
        for (int cf = 0; cf < 4; ++cf) {
            bfr[cf][0] = *(const f16x8*)(bp[cf] + kt * 64);
            bfr[cf][1] = *(const f16x8*)(bp[cf] + kt * 64 + 32);
        }
        #pragma unroll
        for (int cf = 0; cf < 4; ++cf)
            #pragma unroll
            for (int rf = 0; rf < 4; ++rf)
                #pragma unroll
                for (int kb = 0; kb < 2; ++kb)
                    acc[rf][cf] = __builtin_amdgcn_mfma_f32_16x16x32_f16(
                        af[rf][kb], bfr[cf][kb], acc[rf][cf], 0, 0, 0);
    };

    LOAD(RA, 0);
    COMMIT(RA, 0);
    if (KTILES > 1) LOAD(RB, 1);
    #pragma unroll
    for (int kt2 = 0; kt2 < KTILES; kt2 += 2) {
        __syncthreads();
        TILE(0, kt2);
        if (kt2 + 1 < KTILES) COMMIT(RB, 1);
        if (kt2 + 2 < KTILES) LOAD(RA, kt2 + 2);
        if (kt2 + 1 < KTILES) {
            __syncthreads();
            TILE(1, kt2 + 1);
            if (kt2 + 2 < KTILES) COMMIT(RA, 0);
            if (kt2 + 3 < KTILES) LOAD(RB, kt2 + 3);
        }
    }

    #pragma unroll
    for (int rf = 0; rf < 4; ++rf) {
        #pragma unroll
        for (int j = 0; j < 4; ++j) {
            const int row = row0 + rf * 16 + ((l >> 4) * 4) + j;
            if (row >= NNODES) continue;
            #pragma unroll
            for (int cf = 0; cf < 4; ++cf) {
                const int col = wv * 64 + cf * 16 + (l & 15);
                (by ? Cf2 : Cf)[(size_t)row * HDIM + col] = acc[rf][cf][j];
            }
        }
    }
}

// ---------------------------------------------------------------------------
// combine: xh = f16(P0 + P1 + b)
// ---------------------------------------------------------------------------
__global__ __launch_bounds__(256) void combine_k(
    const float* __restrict__ P0, const float* __restrict__ P1,
    const float* __restrict__ b, f16* __restrict__ xh)
{
    const int t = blockIdx.x * 256 + threadIdx.x;
    const int row = t >> 6;
    const int c = (t & 63) * 4;
    if (row >= NNODES) return;
    const float4 a = *(const float4*)(P0 + (size_t)row * HDIM + c);
    const float4 d = *(const float4*)(P1 + (size_t)row * HDIM + c);
    const float4 bb = *(const float4*)(b + c);
    f16x4 r;
    r[0] = (f16)(a.x + d.x + bb.x); r[1] = (f16)(a.y + d.y + bb.y);
    r[2] = (f16)(a.z + d.z + bb.z); r[3] = (f16)(a.w + d.w + bb.w);
    *(f16x4*)(xh + (size_t)row * HDIM + c) = r;
}

// ---------------------------------------------------------------------------
// ONE fused weight-pack kernel (replaces 14 dispatches).
// dst layout: [lin0tA 163840][lin0tB 163840][W2t 262144][W1t 262144]
//             [W3t 262144][WtC 524288]  (f16 elements)
// ---------------------------------------------------------------------------
__global__ __launch_bounds__(256) void pack_all_k(
    const float* __restrict__ lin0_W,
    const float* __restrict__ W2, const float* __restrict__ W1,
    const float* __restrict__ W3,
    const float* __restrict__ Wn, const float* __restrict__ Wr,
    f16* __restrict__ dst)
{
    int idx = blockIdx.x * 256 + threadIdx.x;
    const int total = 163840 * 2 + 262144 * 3 + 524288;
    if (idx >= total) return;
    f16* d = dst + idx;
    if (idx < 327680) {                       // lin0tA | lin0tB
        const int half = idx / 163840;
        int r = idx % 163840;
        const int col = r / 640, k = r % 640;
        *d = (f16)lin0_W[(size_t)(k + half * 640) * 256 + col];
        return;
    }
    idx -= 327680;
    if (idx < 786432) {                       // W2t | W1t | W3t
        const int which = idx / 262144;
        int r = idx % 262144;
        const int i = r / 65536; r %= 65536;
        const int col = r / 256, k = r % 256;
        const float* W = (which == 0) ? W2 : (which == 1) ? W1 : W3;
        *d = (f16)W[(size_t)i * 65536 + k * 256 + col];
        return;
    }
    idx -= 786432;                            // WtC
    const int i = idx / 131072; int r = idx % 131072;
    const int col = r / 512, k = r % 512;
    *d = (f16)(k < 256 ? Wn[(size_t)i * 65536 + k * 256 + col]
                       : Wr[(size_t)i * 65536 + (k - 256) * 256 + col]);
}

// ---------------------------------------------------------------------------
// CSR build
// ---------------------------------------------------------------------------
__global__ __launch_bounds__(256) void count_k(
    const int* __restrict__ dstIdx, int* __restrict__ counts)
{
    const int e = blockIdx.x * 256 + threadIdx.x;
    if (e < NEDGES) atomicAdd(&counts[dstIdx[e]], 1);
}

__global__ __launch_bounds__(1024) void scan_k(
    const int* __restrict__ counts, int* __restrict__ starts)
{
    __shared__ int sm[1024];
    __shared__ int s_off;
    if (threadIdx.x == 0) s_off = 0;
    __syncthreads();
    for (int base = 0; base < NNODES; base += 1024) {
        const int i = base + threadIdx.x;
        const int v = (i < NNODES) ? counts[i] : 0;
        sm[threadIdx.x] = v;
        __syncthreads();
        for (int ofs = 1; ofs < 1024; ofs <<= 1) {
            const int t = (threadIdx.x >= ofs) ? sm[threadIdx.x - ofs] : 0;
            __syncthreads();
            sm[threadIdx.x] += t;
            __syncthreads();
        }
        const int incl = sm[threadIdx.x];
        const int off = s_off;
        if (i < NNODES) starts[i] = off + incl - v;
        __syncthreads();
        if (threadIdx.x == 1023) s_off = off + incl;
        __syncthreads();
    }
    if (threadIdx.x == 0) starts[NNODES] = s_off;
}

__global__ __launch_bounds__(256) void fillcsr_k(
    const int* __restrict__ srcIdx, const int* __restrict__ dstIdx,
    int* __restrict__ cursor, int* __restrict__ csr)
{
    const int e = blockIdx.x * 256 + threadIdx.x;
    if (e >= NEDGES) return;
    const int d = dstIdx[e];
    const int p = atomicAdd(&cursor[d], 1);
    csr[p] = srcIdx[e];
}

// ---------------------------------------------------------------------------
// gather-sums: one wave per node, unroll-4
// ---------------------------------------------------------------------------
__global__ __launch_bounds__(256) void gather_h_k(   // f16 -> f32
    const f16* __restrict__ rows, const int* __restrict__ csr,
    const int* __restrict__ starts, float* __restrict__ outp)
{
    const int node = (blockIdx.x * 256 + threadIdx.x) >> 6;
    const int lane = threadIdx.x & 63;
    if (node >= NNODES) return;
    const int e0 = starts[node], e1 = starts[node + 1];
    float a0=0,a1=0,a2=0,a3=0, b0=0,b1=0,b2=0,b3=0;
    int e = e0;
    for (; e + 3 < e1; e += 4) {
        const int s0=csr[e], s1=csr[e+1], s2=csr[e+2], s3=csr[e+3];
        f16x4 v0 = *(const f16x4*)(rows + (size_t)s0 * HDIM + lane * 4);
        f16x4 v1 = *(const f16x4*)(rows + (size_t)s1 * HDIM + lane * 4);
        f16x4 v2 = *(const f16x4*)(rows + (size_t)s2 * HDIM + lane * 4);
        f16x4 v3 = *(const f16x4*)(rows + (size_t)s3 * HDIM + lane * 4);
        a0 += (float)v0[0] + (float)v2[0]; a1 += (float)v0[1] + (float)v2[1];
        a2 += (float)v0[2] + (float)v2[2]; a3 += (float)v0[3] + (float)v2[3];
        b0 += (float)v1[0] + (float)v3[0]; b1 += (float)v1[1] + (float)v3[1];
        b2 += (float)v1[2] + (float)v3[2]; b3 += (float)v1[3] + (float)v3[3];
    }
    for (; e < e1; ++e) {
        const int s0 = csr[e];
        f16x4 v0 = *(const f16x4*)(rows + (size_t)s0 * HDIM + lane * 4);
        a0 += (float)v0[0]; a1 += (float)v0[1]; a2 += (float)v0[2]; a3 += (float)v0[3];
    }
    *(float4*)(outp + (size_t)node * HDIM + lane * 4) =
        make_float4(a0 + b0, a1 + b1, a2 + b2, a3 + b3);
}

__global__ __launch_bounds__(256) void gather_g_k(   // f16 -> f16
    const f16* __restrict__ rows, const int* __restrict__ csr,
    const int* __restrict__ starts, f16* __restrict__ outp)
{
    const int node = (blockIdx.x * 256 + threadIdx.x) >> 6;
    const int lane = threadIdx.x & 63;
    if (node >= NNODES) return;
    const int e0 = starts[node], e1 = starts[node + 1];
    float a0=0,a1=0,a2=0,a3=0, b0=0,b1=0,b2=0,b3=0;
    int e = e0;
    for (; e + 3 < e1; e += 4) {
        const int s0=csr[e], s1=csr[e+1], s2=csr[e+2], s3=csr[e+3];
        f16x4 v0 = *(const f16x4*)(rows + (size_t)s0 * HDIM + lane * 4);
        f16x4 v1 = *(const f16x4*)(rows + (size_t)s1 * HDIM + lane * 4);
        f16x4 v2 = *(const f16x4*)(rows + (size_t)s2 * HDIM + lane * 4);
        f16x4 v3 = *(const f16x4*)(rows + (size_t)s3 * HDIM + lane * 4);
        a0 += (float)v0[0] + (float)v2[0]; a1 += (float)v0[1] + (float)v2[1];
        a2 += (float)v0[2] + (float)v2[2]; a3 += (float)v0[3] + (float)v2[3];
        b0 += (float)v1[0] + (float)v3[0]; b1 += (float)v1[1] + (float)v3[1];
        b2 += (float)v1[2] + (float)v3[2]; b3 += (float)v1[3] + (float)v3[3];
    }
    for (; e < e1; ++e) {
        const int s0 = csr[e];
        f16x4 v0 = *(const f16x4*)(rows + (size_t)s0 * HDIM + lane * 4);
        a0 += (float)v0[0]; a1 += (float)v0[1]; a2 += (float)v0[2]; a3 += (float)v0[3];
    }
    f16x4 r;
    r[0] = (f16)(a0 + b0); r[1] = (f16)(a1 + b1);
    r[2] = (f16)(a2 + b2); r[3] = (f16)(a3 + b3);
    *(f16x4*)(outp + (size_t)node * HDIM + lane * 4) = r;
}

__global__ __launch_bounds__(256) void fill1_k(float* __restrict__ p, int n)
{
    const int t = blockIdx.x * 256 + threadIdx.x;
    if (t < n) p[t] = 1.0f;
}

// ---------------------------------------------------------------------------
extern "C" void kernel_launch(void* const* d_in, const int* in_sizes, int n_in,
                              void* d_out, int out_size, void* d_ws, size_t ws_size,
                              hipStream_t stream)
{
    const int*   edge   = (const int*)d_in[1];
    const int*   src    = edge;
    const int*   dst    = edge + NEDGES;
    const float* esm    = (const float*)d_in[2];
    const float* lin0_W = (const float*)d_in[4];
    const float* lin0_b = (const float*)d_in[5];
    const float* wc_W1  = (const float*)d_in[6];
    const float* wc_b1  = (const float*)d_in[7];
    const float* wc_W2  = (const float*)d_in[8];
    const float* wc_b2  = (const float*)d_in[9];
    const float* wc_W3  = (const float*)d_in[10];
    const float* wc_b3  = (const float*)d_in[11];
    const float* sc_Wn  = (const float*)d_in[12];
    const float* sc_bn  = (const float*)d_in[13];
    const float* sc_Wr  = (const float*)d_in[14];
    float* out = (float*)d_out;

    const size_t NH = (size_t)NNODES * HDIM;
    float* ws    = (float*)d_ws;
    float* aggf  = ws;                    // f32 [N,256]  (also lin0 partial P0)
    float* part1 = ws + NH;               // f32 [N,256]  (lin0 partial P1)
    f16*   xhA   = (f16*)(ws + 2 * NH);   // f16 [N,256]  x ping
    f16*   xhB   = xhA + NH;              // f16 [N,256]  x pong
    f16*   hnb   = xhB + NH;              // f16 [N,256]  h_nb, then xg
    f16*   agg2  = hnb + NH;              // f16 [N,256]
    f16*   xw1h  = agg2 + NH;             // f16 [N,256]  xm@W1 + b1
    f16*   maskh = xw1h + NH;             // f16 [N,256]
    f16*   wpack = maskh + NH;            // packed weights (see pack_all_k)
    f16*   lin0tA = wpack;                // 163840
    f16*   lin0tB = lin0tA + 163840;      // 163840
    f16*   W2t   = lin0tB + 163840;       // 262144
    f16*   W1t   = W2t + 262144;          // 262144
    f16*   W3t   = W1t + 262144;          // 262144
    f16*   WtC   = W3t + 262144;          // 524288
    int*   iws    = (int*)(WtC + 524288);
    int*   counts = iws;
    int*   starts = iws + NNODES;
    int*   cursor = iws + 2 * NNODES + 1;
    int*   csr    = iws + 3 * NNODES + 2;

    const dim3 blk(256);
    const int gemmGrid = (NNODES + 63) / 64;           // 782
    const int edgeGrid = (NEDGES + 255) / 256;
    const int waveGrid = (NNODES * 64) / 256;

    // ---- CSR build
    hipMemsetAsync(counts, 0, NNODES * sizeof(int), stream);
    count_k<<<edgeGrid, blk, 0, stream>>>(dst, counts);
    scan_k<<<1, 1024, 0, stream>>>(counts, starts);
    hipMemcpyAsync(cursor, starts, NNODES * sizeof(int),
                   hipMemcpyDeviceToDevice, stream);
    fillcsr_k<<<edgeGrid, blk, 0, stream>>>(src, dst, cursor, csr);

    // ---- all weight packs in ONE dispatch
    pack_all_k<<<(1638400 + 255) / 256, blk, 0, stream>>>(
        lin0_W, wc_W2, wc_W1, wc_W3, sc_Wn, sc_Wr, wpack);

    // ---- lin0 K-split: P0/P1 partials, then combine into xhA
    lin0_k<10><<<dim3(gemmGrid, 2), blk, 0, stream>>>(
        esm, FIN, lin0tA, lin0tB, aggf, part1);
    combine_k<<<waveGrid, blk, 0, stream>>>(aggf, part1, lin0_b, xhA);

    for (int i = 0; i < NLAYERS; ++i) {
        const size_t bo = (size_t)i * HDIM;
        const f16* w2 = W2t + i * 65536;
        const f16* w1 = W1t + i * 65536;
        const f16* w3 = W3t + i * 65536;
        const f16* wc = WtC + i * 131072;
        const f16* xcur = (i & 1) ? xhB : xhA;    // double-buffered x
        f16*       xnew = (i & 1) ? xhA : xhB;    // (R8 race fix)

        // fused y-quad: wsel0 -> hnb=f16(xm@W2+b2); wsel1 -> xw1h=f16(xm@W1+b1)
        if (i == 0) {
            dgemm_k<DSRC_H, DEPI_W2W1H, 8><<<dim3(gemmGrid, 4), blk, 0, stream>>>(
                nullptr, xcur, nullptr, nullptr, nullptr, w2, w1,
                wc_b2 + bo, wc_b1 + bo, nullptr, 0, hnb, xw1h);
        } else {
            dgemm_k<DSRC_MULH, DEPI_W2W1H, 8><<<dim3(gemmGrid, 4), blk, 0, stream>>>(
                nullptr, xcur, maskh, nullptr, nullptr, w2, w1,
                wc_b2 + bo, wc_b1 + bo, nullptr, 0, hnb, xw1h);
        }
        // agg = segment_sum(h_nb[src], dst)   (f32 accum)
        gather_h_k<<<waveGrid, blk, 0, stream>>>(hnb, csr, starts, aggf);
        // mask = sigmoid(relu(agg + xw1h)@W3 + b3); xg = xcur*mask  (both f16)
        dgemm_k<DSRC_ADDRELU, DEPI_MASKXG, 8><<<dim3(gemmGrid, 2), blk, 0, stream>>>(
            aggf, nullptr, xw1h, nullptr, xcur, w3, nullptr,
            wc_b3 + bo, nullptr, nullptr, 0, hnb, maskh);
        // agg2 = segment_sum(xg[src], dst)
        gather_g_k<<<waveGrid, blk, 0, stream>>>(hnb, csr, starts, agg2);
        // x_new = relu([agg2 | xcur]@[Wn;Wr] + bn) -> d_out slice i (+ xnew f16)
        dgemm_k<DSRC_CATH, DEPI_CATH, 16><<<dim3(gemmGrid, 2), blk, 0, stream>>>(
            nullptr, agg2, nullptr, xcur, nullptr, wc, nullptr,
            sc_bn + bo, nullptr, out + (size_t)i * HDIM, LDOUT, xnew, nullptr);
    }

    // node_mask: all true
    const size_t maskOff = (size_t)NNODES * LDOUT;
    fill1_k<<<(NNODES + 255) / 256, blk, 0, stream>>>(out + maskOff, NNODES);
}

// Round 10
// 1378.267 us; speedup vs baseline: 1.5033x; 1.5033x over previous
//
#include <hip/hip_runtime.h>

#define NNODES 50000
#define HDIM 256
#define NLAYERS 4
#define NEDGES 800000
#define FIN 1280
#define LDOUT 1024

typedef _Float16 f16;
typedef __attribute__((ext_vector_type(8))) _Float16 f16x8;
typedef __attribute__((ext_vector_type(4))) _Float16 f16x4;
typedef __attribute__((ext_vector_type(4))) float f32x4;

enum { SRC_H = 0, SRC_MULH = 1, SRC_ADDRELU_HH = 2, SRC_CATH = 3 };
enum { EPI_W2W1H = 0, EPI_MASKXG = 1, EPI_CATH = 2 };

// ---------------------------------------------------------------------------
// Layer MFMA GEMM (R7 structure, best measured): BM=64 x BN=256, BK=64,
// 256 thr = 4 waves (wave wv owns cols wv*64..+64).  Double-buffered LDS
// A-tile + depth-2 reg prefetch (two named reg sets, x2 unroll -> static idx).
// All staging inputs f16 now (agg kept f16).  blockIdx.y multiplexes the
// W2|W1 weight pair.  RACE RULE: in-place xh update is safe ONLY with
// gridDim.y==1 (block reads/writes its own 64 rows; epilogue after K-loop).
// MFMA layouts refcheck-validated R3-R9: A row=l&15, k=(l>>4)*8+j (+32kb);
// B col=l&15 (col-major Wt); C/D col=l&15, row=(l>>4)*4+reg.
// ---------------------------------------------------------------------------
template<int SRC, int EPI, int KTILES>
__global__ __launch_bounds__(256) void mgemm_k(
    const f16*  __restrict__ A3,      // xh / agg1 / agg2
    const f16*  __restrict__ A5,      // maskh (MULH) / xw1h (ADDRELU_HH)
    const f16*  __restrict__ A4,      // xh (CATH, k>=256)
    const f16*  __restrict__ Xh,      // xh (MASKXG epilogue)
    const f16*  __restrict__ Wt,      // [256 cols][K] col-major f16
    const f16*  __restrict__ Wt2,     // W1 (W2W1 pair)
    const float* __restrict__ bias,
    const float* __restrict__ bias2,
    float* __restrict__ Cf, int ldc,
    f16*  __restrict__ Ch,
    f16*  __restrict__ Ch2)
{
    constexpr int K = KTILES * 64;
    __shared__ f16 Asm[2][4096];      // 2 x 8 KB

    const int row0 = blockIdx.x * 64;
    const int by = blockIdx.y;
    const int tid = threadIdx.x;
    const int wv = tid >> 6;
    const int l = tid & 63;

    f32x4 acc[4][4] = {};

    // staging: thread t -> row sr=t>>2, k-cols [sc0, sc0+16)
    const int sr = tid >> 2;
    const int sc0 = (tid & 3) * 16;
    const int grow = row0 + sr;
    const bool rok = grow < NNODES;
    const int lane_base0 =
        (((sc0 >> 5) * 4 + (sr >> 4)) * 64 + (sr & 15) + (((sc0 & 31) >> 3) * 16)) * 8;
    const int lane_base1 = lane_base0 + 128;

    const f16* Wsel = (EPI == EPI_W2W1H && by) ? Wt2 : Wt;
    const f16* bp[4];
    #pragma unroll
    for (int cf = 0; cf < 4; ++cf)
        bp[cf] = Wsel + (size_t)(wv * 64 + cf * 16 + (l & 15)) * K + ((l >> 4) * 8);

    struct SReg { f16x8 h0, h1, g0, g1; };
    SReg RA, RB;

    auto LOAD = [&](SReg& r, int kt) {
        if (!rok) return;
        const int k0 = kt * 64 + sc0;
        if constexpr (SRC == SRC_CATH) {
            const f16* p = (k0 < HDIM)
                ? (A3 + (size_t)grow * HDIM + k0)
                : (A4 + (size_t)grow * HDIM + (k0 - HDIM));
            r.h0 = *(const f16x8*)p;  r.h1 = *(const f16x8*)(p + 8);
        } else {
            const f16* p = A3 + (size_t)grow * HDIM + k0;
            r.h0 = *(const f16x8*)p;  r.h1 = *(const f16x8*)(p + 8);
            if constexpr (SRC == SRC_MULH || SRC == SRC_ADDRELU_HH) {
                const f16* q = A5 + (size_t)grow * HDIM + k0;
                r.g0 = *(const f16x8*)q;  r.g1 = *(const f16x8*)(q + 8);
            }
        }
    };

    auto COMMIT = [&](const SReg& r, int b) {
        f16x8 av0, av1;
        #pragma unroll
        for (int i = 0; i < 8; ++i) { av0[i] = (f16)0.f; av1[i] = (f16)0.f; }
        if (rok) {
            if constexpr (SRC == SRC_H || SRC == SRC_CATH) {
                av0 = r.h0; av1 = r.h1;
            } else if constexpr (SRC == SRC_MULH) {
                #pragma unroll
                for (int i = 0; i < 8; ++i) {
                    av0[i] = (f16)((float)r.h0[i] * (float)r.g0[i]);
                    av1[i] = (f16)((float)r.h1[i] * (float)r.g1[i]);
                }
            } else { // SRC_ADDRELU_HH: relu(agg + xw1h) — b1 folded into xw1h
                #pragma unroll
                for (int i = 0; i < 8; ++i) {
                    av0[i] = (f16)fmaxf((float)r.h0[i] + (float)r.g0[i], 0.f);
                    av1[i] = (f16)fmaxf((float)r.h1[i] + (float)r.g1[i], 0.f);
                }
            }
        }
        *(f16x8*)(&Asm[b][lane_base0]) = av0;
        *(f16x8*)(&Asm[b][lane_base1]) = av1;
    };

    auto TILE = [&](int b, int kt) {
        f16x8 af[4][2];
        #pragma unroll
        for (int rf = 0; rf < 4; ++rf)
            #pragma unroll
            for (int kb = 0; kb < 2; ++kb)
                af[rf][kb] = *(const f16x8*)(&Asm[b][((kb * 4 + rf) * 64 + l) * 8]);
        f16x8 bfr[4][2];
        #pragma unroll
        for (int cf = 0; cf < 4; ++cf) {
            bfr[cf][0] = *(const f16x8*)(bp[cf] + kt * 64);
            bfr[cf][1] = *(const f16x8*)(bp[cf] + kt * 64 + 32);
        }
        #pragma unroll
        for (int cf = 0; cf < 4; ++cf)
            #pragma unroll
            for (int rf = 0; rf < 4; ++rf)
                #pragma unroll
                for (int kb = 0; kb < 2; ++kb)
                    acc[rf][cf] = __builtin_amdgcn_mfma_f32_16x16x32_f16(
                        af[rf][kb], bfr[cf][kb], acc[rf][cf], 0, 0, 0);
    };

    // depth-2 pipeline: loads for tile t+2 in flight while tile t computes
    LOAD(RA, 0);
    COMMIT(RA, 0);
    if (KTILES > 1) LOAD(RB, 1);
    #pragma unroll
    for (int kt2 = 0; kt2 < KTILES; kt2 += 2) {
        __syncthreads();
        TILE(0, kt2);
        if (kt2 + 1 < KTILES) COMMIT(RB, 1);
        if (kt2 + 2 < KTILES) LOAD(RA, kt2 + 2);
        if (kt2 + 1 < KTILES) {
            __syncthreads();
            TILE(1, kt2 + 1);
            if (kt2 + 2 < KTILES) COMMIT(RA, 0);
            if (kt2 + 3 < KTILES) LOAD(RB, kt2 + 3);
        }
    }

    // ---- epilogue
    #pragma unroll
    for (int rf = 0; rf < 4; ++rf) {
        #pragma unroll
        for (int j = 0; j < 4; ++j) {
            const int row = row0 + rf * 16 + ((l >> 4) * 4) + j;
            if (row >= NNODES) continue;
            #pragma unroll
            for (int cf = 0; cf < 4; ++cf) {
                const int col = wv * 64 + cf * 16 + (l & 15);
                float v = acc[rf][cf][j];
                if constexpr (EPI == EPI_W2W1H) {
                    if (by == 0) Ch[(size_t)row * HDIM + col]  = (f16)(v + bias[col]);
                    else         Ch2[(size_t)row * HDIM + col] = (f16)(v + bias2[col]);
                } else if constexpr (EPI == EPI_MASKXG) {
                    const float m = 1.f / (1.f + expf(-(v + bias[col])));
                    Ch2[(size_t)row * HDIM + col] = (f16)m;
                    Ch[(size_t)row * HDIM + col] =
                        (f16)((float)Xh[(size_t)row * HDIM + col] * m);
                } else { // EPI_CATH
                    const float r = fmaxf(v + bias[col], 0.f);
                    Cf[(size_t)row * ldc + col] = r;
                    Ch[(size_t)row * HDIM + col] = (f16)r;
                }
            }
        }
    }
}

// ---------------------------------------------------------------------------
// lin0 GEMM (verified R7/R9, 149us): BM=64 x BN=256, BK=64, LDS dbuf +
// depth-2 reg prefetch; blockIdx.y = K-half (K-split x2).
// ---------------------------------------------------------------------------
template<int KTILES>
__global__ __launch_bounds__(256) void lin0_k(
    const float* __restrict__ A1, int lda1,
    const f16*  __restrict__ WtA, const f16* __restrict__ WtB,
    float* __restrict__ Cf, float* __restrict__ Cf2)
{
    constexpr int K = KTILES * 64;
    __shared__ f16 Asm[2][4096];

    const int row0 = blockIdx.x * 64;
    const int by = blockIdx.y;
    const int tid = threadIdx.x;
    const int wv = tid >> 6;
    const int l = tid & 63;

    f32x4 acc[4][4] = {};

    const int sr = tid >> 2;
    const int sc0 = (tid & 3) * 16;
    const int grow = row0 + sr;
    const bool rok = grow < NNODES;
    const int kg = by * K;
    const int lane_base0 =
        (((sc0 >> 5) * 4 + (sr >> 4)) * 64 + (sr & 15) + (((sc0 & 31) >> 3) * 16)) * 8;
    const int lane_base1 = lane_base0 + 128;

    const f16* Wsel = by ? WtB : WtA;
    const f16* bp[4];
    #pragma unroll
    for (int cf = 0; cf < 4; ++cf)
        bp[cf] = Wsel + (size_t)(wv * 64 + cf * 16 + (l & 15)) * K + ((l >> 4) * 8);

    struct SReg { float4 f0, f1, f2, f3; };
    SReg RA, RB;

    auto LOAD = [&](SReg& r, int kt) {
        if (!rok) return;
        const float* p = A1 + (size_t)grow * lda1 + kg + kt * 64 + sc0;
        r.f0 = *(const float4*)(p + 0);  r.f1 = *(const float4*)(p + 4);
        r.f2 = *(const float4*)(p + 8);  r.f3 = *(const float4*)(p + 12);
    };

    auto COMMIT = [&](const SReg& r, int b) {
        f16x8 av0, av1;
        #pragma unroll
        for (int i = 0; i < 8; ++i) { av0[i] = (f16)0.f; av1[i] = (f16)0.f; }
        if (rok) {
            av0[0]=(f16)r.f0.x; av0[1]=(f16)r.f0.y; av0[2]=(f16)r.f0.z; av0[3]=(f16)r.f0.w;
            av0[4]=(f16)r.f1.x; av0[5]=(f16)r.f1.y; av0[6]=(f16)r.f1.z; av0[7]=(f16)r.f1.w;
            av1[0]=(f16)r.f2.x; av1[1]=(f16)r.f2.y; av1[2]=(f16)r.f2.z; av1[3]=(f16)r.f2.w;
            av1[4]=(f16)r.f3.x; av1[5]=(f16)r.f3.y; av1[6]=(f16)r.f3.z; av1[7]=(f16)r.f3.w;
        }
        *(f16x8*)(&Asm[b][lane_base0]) = av0;
        *(f16x8*)(&Asm[b][lane_base1]) = av1;
    };

    auto TILE = [&](int b, int kt) {
        f16x8 af[4][2];
        #pragma unroll
        for (int rf = 0; rf < 4; ++rf)
            #pragma unroll
            for (int kb = 0; kb < 2; ++kb)
                af[rf][kb] = *(const f16x8*)(&Asm[b][((kb * 4 + rf) * 64 + l) * 8]);
        f16x8 bfr[4][2];
        #pragma unroll
        for (int cf = 0; cf < 4; ++cf) {
            bfr[cf][0] = *(const f16x8*)(bp[cf] + kt * 64);
            bfr[cf][1] = *(const f16x8*)(bp[cf] + kt * 64 + 32);
        }
        #pragma unroll
        for (int cf = 0; cf < 4; ++cf)
            #pragma unroll
            for (int rf = 0; rf < 4; ++rf)
                #pragma unroll
                for (int kb = 0; kb < 2; ++kb)
                    acc[rf][cf] = __builtin_amdgcn_mfma_f32_16x16x32_f16(
                        af[rf][kb], bfr[cf][kb], acc[rf][cf], 0, 0, 0);
    };

    LOAD(RA, 0);
    COMMIT(RA, 0);
    if (KTILES > 1) LOAD(RB, 1);
    #pragma unroll
    for (int kt2 = 0; kt2 < KTILES; kt2 += 2) {
        __syncthreads();
        TILE(0, kt2);
        if (kt2 + 1 < KTILES) COMMIT(RB, 1);
        if (kt2 + 2 < KTILES) LOAD(RA, kt2 + 2);
        if (kt2 + 1 < KTILES) {
            __syncthreads();
            TILE(1, kt2 + 1);
            if (kt2 + 2 < KTILES) COMMIT(RA, 0);
            if (kt2 + 3 < KTILES) LOAD(RB, kt2 + 3);
        }
    }

    #pragma unroll
    for (int rf = 0; rf < 4; ++rf) {
        #pragma unroll
        for (int j = 0; j < 4; ++j) {
            const int row = row0 + rf * 16 + ((l >> 4) * 4) + j;
            if (row >= NNODES) continue;
            #pragma unroll
            for (int cf = 0; cf < 4; ++cf) {
                const int col = wv * 64 + cf * 16 + (l & 15);
                (by ? Cf2 : Cf)[(size_t)row * HDIM + col] = acc[rf][cf][j];
            }
        }
    }
}

// ---------------------------------------------------------------------------
// combine: xh = f16(P0 + P1 + b)
// ---------------------------------------------------------------------------
__global__ __launch_bounds__(256) void combine_k(
    const float* __restrict__ P0, const float* __restrict__ P1,
    const float* __restrict__ b, f16* __restrict__ xh)
{
    const int t = blockIdx.x * 256 + threadIdx.x;
    const int row = t >> 6;
    const int c = (t & 63) * 4;
    if (row >= NNODES) return;
    const float4 a = *(const float4*)(P0 + (size_t)row * HDIM + c);
    const float4 d = *(const float4*)(P1 + (size_t)row * HDIM + c);
    const float4 bb = *(const float4*)(b + c);
    f16x4 r;
    r[0] = (f16)(a.x + d.x + bb.x); r[1] = (f16)(a.y + d.y + bb.y);
    r[2] = (f16)(a.z + d.z + bb.z); r[3] = (f16)(a.w + d.w + bb.w);
    *(f16x4*)(xh + (size_t)row * HDIM + c) = r;
}

// ---------------------------------------------------------------------------
// ONE fused weight-pack kernel (verified in passing R9).
// dst layout: [lin0tA 163840][lin0tB 163840][W2t 262144][W1t 262144]
//             [W3t 262144][WtC 524288]  (f16 elements)
// ---------------------------------------------------------------------------
__global__ __launch_bounds__(256) void pack_all_k(
    const float* __restrict__ lin0_W,
    const float* __restrict__ W2, const float* __restrict__ W1,
    const float* __restrict__ W3,
    const float* __restrict__ Wn, const float* __restrict__ Wr,
    f16* __restrict__ dst)
{
    int idx = blockIdx.x * 256 + threadIdx.x;
    const int total = 163840 * 2 + 262144 * 3 + 524288;
    if (idx >= total) return;
    f16* d = dst + idx;
    if (idx < 327680) {                       // lin0tA | lin0tB
        const int half = idx / 163840;
        int r = idx % 163840;
        const int col = r / 640, k = r % 640;
        *d = (f16)lin0_W[(size_t)(k + half * 640) * 256 + col];
        return;
    }
    idx -= 327680;
    if (idx < 786432) {                       // W2t | W1t | W3t
        const int which = idx / 262144;
        int r = idx % 262144;
        const int i = r / 65536; r %= 65536;
        const int col = r / 256, k = r % 256;
        const float* W = (which == 0) ? W2 : (which == 1) ? W1 : W3;
        *d = (f16)W[(size_t)i * 65536 + k * 256 + col];
        return;
    }
    idx -= 786432;                            // WtC
    const int i = idx / 131072; int r = idx % 131072;
    const int col = r / 512, k = r % 512;
    *d = (f16)(k < 256 ? Wn[(size_t)i * 65536 + k * 256 + col]
                       : Wr[(size_t)i * 65536 + (k - 256) * 256 + col]);
}

// ---------------------------------------------------------------------------
// CSR build
// ---------------------------------------------------------------------------
__global__ __launch_bounds__(256) void count_k(
    const int* __restrict__ dstIdx, int* __restrict__ counts)
{
    const int e = blockIdx.x * 256 + threadIdx.x;
    if (e < NEDGES) atomicAdd(&counts[dstIdx[e]], 1);
}

__global__ __launch_bounds__(1024) void scan_k(
    const int* __restrict__ counts, int* __restrict__ starts)
{
    __shared__ int sm[1024];
    __shared__ int s_off;
    if (threadIdx.x == 0) s_off = 0;
    __syncthreads();
    for (int base = 0; base < NNODES; base += 1024) {
        const int i = base + threadIdx.x;
        const int v = (i < NNODES) ? counts[i] : 0;
        sm[threadIdx.x] = v;
        __syncthreads();
        for (int ofs = 1; ofs < 1024; ofs <<= 1) {
            const int t = (threadIdx.x >= ofs) ? sm[threadIdx.x - ofs] : 0;
            __syncthreads();
            sm[threadIdx.x] += t;
            __syncthreads();
        }
        const int incl = sm[threadIdx.x];
        const int off = s_off;
        if (i < NNODES) starts[i] = off + incl - v;
        __syncthreads();
        if (threadIdx.x == 1023) s_off = off + incl;
        __syncthreads();
    }
    if (threadIdx.x == 0) starts[NNODES] = s_off;
}

__global__ __launch_bounds__(256) void fillcsr_k(
    const int* __restrict__ srcIdx, const int* __restrict__ dstIdx,
    int* __restrict__ cursor, int* __restrict__ csr)
{
    const int e = blockIdx.x * 256 + threadIdx.x;
    if (e >= NEDGES) return;
    const int d = dstIdx[e];
    const int p = atomicAdd(&cursor[d], 1);
    csr[p] = srcIdx[e];
}

// ---------------------------------------------------------------------------
// gather-sum: one wave per node, f16 rows -> f32 accum -> f16 out, unroll-4
// ---------------------------------------------------------------------------
__global__ __launch_bounds__(256) void gather_g_k(
    const f16* __restrict__ rows, const int* __restrict__ csr,
    const int* __restrict__ starts, f16* __restrict__ outp)
{
    const int node = (blockIdx.x * 256 + threadIdx.x) >> 6;
    const int lane = threadIdx.x & 63;
    if (node >= NNODES) return;
    const int e0 = starts[node], e1 = starts[node + 1];
    float a0=0,a1=0,a2=0,a3=0, b0=0,b1=0,b2=0,b3=0;
    int e = e0;
    for (; e + 3 < e1; e += 4) {
        const int s0=csr[e], s1=csr[e+1], s2=csr[e+2], s3=csr[e+3];
        f16x4 v0 = *(const f16x4*)(rows + (size_t)s0 * HDIM + lane * 4);
        f16x4 v1 = *(const f16x4*)(rows + (size_t)s1 * HDIM + lane * 4);
        f16x4 v2 = *(const f16x4*)(rows + (size_t)s2 * HDIM + lane * 4);
        f16x4 v3 = *(const f16x4*)(rows + (size_t)s3 * HDIM + lane * 4);
        a0 += (float)v0[0] + (float)v2[0]; a1 += (float)v0[1] + (float)v2[1];
        a2 += (float)v0[2] + (float)v2[2]; a3 += (float)v0[3] + (float)v2[3];
        b0 += (float)v1[0] + (float)v3[0]; b1 += (float)v1[1] + (float)v3[1];
        b2 += (float)v1[2] + (float)v3[2]; b3 += (float)v1[3] + (float)v3[3];
    }
    for (; e < e1; ++e) {
        const int s0 = csr[e];
        f16x4 v0 = *(const f16x4*)(rows + (size_t)s0 * HDIM + lane * 4);
        a0 += (float)v0[0]; a1 += (float)v0[1]; a2 += (float)v0[2]; a3 += (float)v0[3];
    }
    f16x4 r;
    r[0] = (f16)(a0 + b0); r[1] = (f16)(a1 + b1);
    r[2] = (f16)(a2 + b2); r[3] = (f16)(a3 + b3);
    *(f16x4*)(outp + (size_t)node * HDIM + lane * 4) = r;
}

__global__ __launch_bounds__(256) void fill1_k(float* __restrict__ p, int n)
{
    const int t = blockIdx.x * 256 + threadIdx.x;
    if (t < n) p[t] = 1.0f;
}

// ---------------------------------------------------------------------------
extern "C" void kernel_launch(void* const* d_in, const int* in_sizes, int n_in,
                              void* d_out, int out_size, void* d_ws, size_t ws_size,
                              hipStream_t stream)
{
    const int*   edge   = (const int*)d_in[1];
    const int*   src    = edge;
    const int*   dst    = edge + NEDGES;
    const float* esm    = (const float*)d_in[2];
    const float* lin0_W = (const float*)d_in[4];
    const float* lin0_b = (const float*)d_in[5];
    const float* wc_W1  = (const float*)d_in[6];
    const float* wc_b1  = (const float*)d_in[7];
    const float* wc_W2  = (const float*)d_in[8];
    const float* wc_b2  = (const float*)d_in[9];
    const float* wc_W3  = (const float*)d_in[10];
    const float* wc_b3  = (const float*)d_in[11];
    const float* sc_Wn  = (const float*)d_in[12];
    const float* sc_bn  = (const float*)d_in[13];
    const float* sc_Wr  = (const float*)d_in[14];
    float* out = (float*)d_out;

    const size_t NH = (size_t)NNODES * HDIM;
    float* ws    = (float*)d_ws;
    float* part0 = ws;                    // f32 [N,256]  lin0 partial P0
    float* part1 = ws + NH;               // f32 [N,256]  lin0 partial P1
    f16*   xh    = (f16*)(ws + 2 * NH);   // f16 [N,256]  current x (in-place ok)
    f16*   hnb   = xh + NH;               // f16 [N,256]  h_nb, then xg
    f16*   agg1  = hnb + NH;              // f16 [N,256]  segment_sum(h_nb)
    f16*   agg2  = agg1 + NH;             // f16 [N,256]  segment_sum(xg)
    f16*   xw1h  = agg2 + NH;             // f16 [N,256]  xm@W1 + b1
    f16*   maskh = xw1h + NH;             // f16 [N,256]
    f16*   wpack = maskh + NH;            // packed weights
    f16*   lin0tA = wpack;                // 163840
    f16*   lin0tB = lin0tA + 163840;      // 163840
    f16*   W2t   = lin0tB + 163840;       // 262144
    f16*   W1t   = W2t + 262144;          // 262144
    f16*   W3t   = W1t + 262144;          // 262144
    f16*   WtC   = W3t + 262144;          // 524288
    int*   iws    = (int*)(WtC + 524288);
    int*   counts = iws;
    int*   starts = iws + NNODES;
    int*   cursor = iws + 2 * NNODES + 1;
    int*   csr    = iws + 3 * NNODES + 2;

    const dim3 blk(256);
    const int gemmGrid = (NNODES + 63) / 64;           // 782
    const int edgeGrid = (NEDGES + 255) / 256;
    const int waveGrid = (NNODES * 64) / 256;          // 12500

    // ---- CSR build
    hipMemsetAsync(counts, 0, NNODES * sizeof(int), stream);
    count_k<<<edgeGrid, blk, 0, stream>>>(dst, counts);
    scan_k<<<1, 1024, 0, stream>>>(counts, starts);
    hipMemcpyAsync(cursor, starts, NNODES * sizeof(int),
                   hipMemcpyDeviceToDevice, stream);
    fillcsr_k<<<edgeGrid, blk, 0, stream>>>(src, dst, cursor, csr);

    // ---- all weight packs in ONE dispatch
    pack_all_k<<<(1638400 + 255) / 256, blk, 0, stream>>>(
        lin0_W, wc_W2, wc_W1, wc_W3, sc_Wn, sc_Wr, wpack);

    // ---- lin0 K-split: P0/P1 partials, then combine into xh
    lin0_k<10><<<dim3(gemmGrid, 2), blk, 0, stream>>>(
        esm, FIN, lin0tA, lin0tB, part0, part1);
    combine_k<<<waveGrid, blk, 0, stream>>>(part0, part1, lin0_b, xh);

    for (int i = 0; i < NLAYERS; ++i) {
        const size_t bo = (size_t)i * HDIM;
        const f16* w2 = W2t + i * 65536;
        const f16* w1 = W1t + i * 65536;
        const f16* w3 = W3t + i * 65536;
        const f16* wc = WtC + i * 131072;

        // fused y-pair: y0: hnb = f16(xm@W2 + b2); y1: xw1h = f16(xm@W1 + b1)
        if (i == 0) {
            mgemm_k<SRC_H, EPI_W2W1H, 4><<<dim3(gemmGrid, 2), blk, 0, stream>>>(
                xh, nullptr, nullptr, nullptr, w2, w1,
                wc_b2 + bo, wc_b1 + bo, nullptr, 0, hnb, xw1h);
        } else {
            mgemm_k<SRC_MULH, EPI_W2W1H, 4><<<dim3(gemmGrid, 2), blk, 0, stream>>>(
                xh, maskh, nullptr, nullptr, w2, w1,
                wc_b2 + bo, wc_b1 + bo, nullptr, 0, hnb, xw1h);
        }
        // agg1 = segment_sum(h_nb[src], dst)  (f16 out, f32 accum)
        gather_g_k<<<waveGrid, blk, 0, stream>>>(hnb, csr, starts, agg1);
        // mask = sigmoid(relu(agg1 + xw1h)@W3 + b3); xg = xh*mask  (both f16)
        mgemm_k<SRC_ADDRELU_HH, EPI_MASKXG, 4><<<gemmGrid, blk, 0, stream>>>(
            agg1, xw1h, nullptr, xh, w3, nullptr,
            wc_b3 + bo, nullptr, nullptr, 0, hnb, maskh);
        // agg2 = segment_sum(xg[src], dst)
        gather_g_k<<<waveGrid, blk, 0, stream>>>(hnb, csr, starts, agg2);
        // x_new = relu([agg2 | xh]@[Wn;Wr] + bn) -> d_out slice i (+ xh f16,
        // in-place safe: gridDim.y==1, epilogue after K-loop, own rows only)
        mgemm_k<SRC_CATH, EPI_CATH, 8><<<gemmGrid, blk, 0, stream>>>(
            agg2, nullptr, xh, nullptr, wc, nullptr,
            sc_bn + bo, nullptr, out + (size_t)i * HDIM, LDOUT, xh, nullptr);
    }

    // node_mask: all true
    const size_t maskOff = (size_t)NNODES * LDOUT;
    fill1_k<<<(NNODES + 255) / 256, blk, 0, stream>>>(out + maskOff, NNODES);
}